// Round 1
// baseline (259.778 us; speedup 1.0000x reference)
//
#include <hip/hip_runtime.h>

#define S_LEN 2048
#define D_DIM 128
#define TK 64
#define KSTR 136   // kbuf row stride (bf16 elems): 128 + 8 pad, 16B-aligned
#define VSTR 72    // vbufT row stride: 64 + 8 pad, 16B-aligned
#define PSTR 72    // pbuf row stride
#define NT (S_LEN / TK)

typedef __attribute__((ext_vector_type(4))) float f32x4;
typedef __attribute__((ext_vector_type(8))) short short8;

static __device__ __forceinline__ unsigned short f2bf(float f) {
  unsigned u = __builtin_bit_cast(unsigned, f);
  return (unsigned short)((u + 0x7fffu + ((u >> 16) & 1u)) >> 16);  // RNE
}

static __device__ __forceinline__ float fc(const float4& f, int i) {
  union { float4 v; float a[4]; } u; u.v = f; return u.a[i];
}

__global__ __launch_bounds__(256, 1)
void attn_kernel(const float* __restrict__ Q, const float* __restrict__ K,
                 const float* __restrict__ V, float* __restrict__ O) {
  __shared__ short kbuf[TK * KSTR];        // 64 x 136 bf16 (K tile, row-major)
  __shared__ short vbufT[D_DIM * VSTR];    // 128 x 72 bf16 (V tile, transposed: [d][s])
  __shared__ short pbuf[4 * 32 * PSTR];    // per-wave 32 x 72 bf16 (P round-trip)

  const int tid  = threadIdx.x;
  const int wave = tid >> 6;
  const int lane = tid & 63;
  const int quad = lane >> 4;
  const int ln   = lane & 15;

  // XCD-aware swizzle: batch pair pinned to one XCD for K/V L2 residency
  const int i     = blockIdx.x;
  const int b     = (i & 7) * 2 + ((i >> 3) & 1);
  const int qtile = i >> 4;                  // 0..15
  const int qbase = qtile * 128 + wave * 32; // this wave's first q row

  const size_t boff = (size_t)b * S_LEN * D_DIM;
  const float* Qb = Q + boff;
  const float* Kb = K + boff;
  const float* Vb = V + boff;

  // ---- Q fragments (A-layout: row=ln, k=quad*8+j), kept in registers ----
  short8 qa[2][4];
#pragma unroll
  for (int rt = 0; rt < 2; ++rt) {
    const float* qp = Qb + (size_t)(qbase + rt * 16 + ln) * D_DIM + quad * 8;
#pragma unroll
    for (int dc = 0; dc < 4; ++dc) {
      float4 a0 = *(const float4*)(qp + dc * 32);
      float4 a1 = *(const float4*)(qp + dc * 32 + 4);
      short8 f;
      f[0] = (short)f2bf(a0.x); f[1] = (short)f2bf(a0.y);
      f[2] = (short)f2bf(a0.z); f[3] = (short)f2bf(a0.w);
      f[4] = (short)f2bf(a1.x); f[5] = (short)f2bf(a1.y);
      f[6] = (short)f2bf(a1.z); f[7] = (short)f2bf(a1.w);
      qa[rt][dc] = f;
    }
  }

  const f32x4 zf = {0.f, 0.f, 0.f, 0.f};
  f32x4 oacc[2][8];
  float m_i[2][4], l_i[2][4];
#pragma unroll
  for (int rt = 0; rt < 2; ++rt) {
#pragma unroll
    for (int df = 0; df < 8; ++df) oacc[rt][df] = zf;
#pragma unroll
    for (int r = 0; r < 4; ++r) { m_i[rt][r] = -1e30f; l_i[rt][r] = 0.f; }
  }

  // ---- prefetch tile 0 into registers ----
  float4 kr[8], vr[8];
  {
#pragma unroll
    for (int j = 0; j < 8; ++j) {
      int idx = tid + j * 256; int row = idx >> 5, c4 = idx & 31;
      kr[j] = *(const float4*)(Kb + row * D_DIM + c4 * 4);
    }
#pragma unroll
    for (int j = 0; j < 2; ++j) {
      int i2 = tid + j * 256; int rg = i2 >> 5, c4 = i2 & 31;
#pragma unroll
      for (int r = 0; r < 4; ++r)
        vr[j * 4 + r] = *(const float4*)(Vb + (rg * 4 + r) * D_DIM + c4 * 4);
    }
  }

  const float SC = 0.08838834764831845f * 1.4426950408889634f; // 1/sqrt(128)*log2(e)
  short* pw = pbuf + wave * 32 * PSTR;

  for (int t = 0; t < NT; ++t) {
    __syncthreads();  // previous tile's LDS reads complete

    // ---- write staged K to LDS (bf16, row-major) ----
#pragma unroll
    for (int j = 0; j < 8; ++j) {
      int idx = tid + j * 256; int row = idx >> 5, c4 = idx & 31;
      unsigned lo = (unsigned)f2bf(kr[j].x) | ((unsigned)f2bf(kr[j].y) << 16);
      unsigned hi = (unsigned)f2bf(kr[j].z) | ((unsigned)f2bf(kr[j].w) << 16);
      *(uint2*)&kbuf[row * KSTR + c4 * 4] = make_uint2(lo, hi);
    }
    // ---- write staged V to LDS transposed via 4x4 micro-transpose ----
#pragma unroll
    for (int j = 0; j < 2; ++j) {
      int i2 = tid + j * 256; int rg = i2 >> 5, c4 = i2 & 31;
#pragma unroll
      for (int dd = 0; dd < 4; ++dd) {
        unsigned lo = (unsigned)f2bf(fc(vr[j * 4 + 0], dd)) |
                      ((unsigned)f2bf(fc(vr[j * 4 + 1], dd)) << 16);
        unsigned hi = (unsigned)f2bf(fc(vr[j * 4 + 2], dd)) |
                      ((unsigned)f2bf(fc(vr[j * 4 + 3], dd)) << 16);
        *(uint2*)&vbufT[(c4 * 4 + dd) * VSTR + rg * 4] = make_uint2(lo, hi);
      }
    }

    // ---- prefetch next tile (in flight during compute) ----
    if (t + 1 < NT) {
      const float* ksrc = Kb + (size_t)(t + 1) * TK * D_DIM;
      const float* vsrc = Vb + (size_t)(t + 1) * TK * D_DIM;
#pragma unroll
      for (int j = 0; j < 8; ++j) {
        int idx = tid + j * 256; int row = idx >> 5, c4 = idx & 31;
        kr[j] = *(const float4*)(ksrc + row * D_DIM + c4 * 4);
      }
#pragma unroll
      for (int j = 0; j < 2; ++j) {
        int i2 = tid + j * 256; int rg = i2 >> 5, c4 = i2 & 31;
#pragma unroll
        for (int r = 0; r < 4; ++r)
          vr[j * 4 + r] = *(const float4*)(vsrc + (rg * 4 + r) * D_DIM + c4 * 4);
      }
    }
    __syncthreads();  // staging visible to all waves

    // ---- S = Q K^T : per wave 2 rowtiles x 4 colfrags, K=128 over 4 MFMAs ----
    f32x4 sacc[2][4];
#pragma unroll
    for (int rt = 0; rt < 2; ++rt)
#pragma unroll
      for (int cf = 0; cf < 4; ++cf) sacc[rt][cf] = zf;

#pragma unroll
    for (int cf = 0; cf < 4; ++cf) {
#pragma unroll
      for (int dc = 0; dc < 4; ++dc) {
        short8 kf = *(const short8*)&kbuf[(cf * 16 + ln) * KSTR + dc * 32 + quad * 8];
        sacc[0][cf] = __builtin_amdgcn_mfma_f32_16x16x32_bf16(qa[0][dc], kf, sacc[0][cf], 0, 0, 0);
        sacc[1][cf] = __builtin_amdgcn_mfma_f32_16x16x32_bf16(qa[1][dc], kf, sacc[1][cf], 0, 0, 0);
      }
    }

    // ---- online softmax (rows = quad*4+r, cols spread over ln & cf) ----
#pragma unroll
    for (int rt = 0; rt < 2; ++rt) {
#pragma unroll
      for (int r = 0; r < 4; ++r) {
        float mn = fmaxf(fmaxf(sacc[rt][0][r], sacc[rt][1][r]),
                         fmaxf(sacc[rt][2][r], sacc[rt][3][r]));
        mn = fmaxf(mn, __shfl_xor(mn, 1));
        mn = fmaxf(mn, __shfl_xor(mn, 2));
        mn = fmaxf(mn, __shfl_xor(mn, 4));
        mn = fmaxf(mn, __shfl_xor(mn, 8));
        float mx = fmaxf(m_i[rt][r], mn);
        float alpha = exp2f((m_i[rt][r] - mx) * SC);
        m_i[rt][r] = mx;
        float rs = 0.f;
#pragma unroll
        for (int cf = 0; cf < 4; ++cf) {
          float p = exp2f((sacc[rt][cf][r] - mx) * SC);
          sacc[rt][cf][r] = p;
          rs += p;
        }
        rs += __shfl_xor(rs, 1);
        rs += __shfl_xor(rs, 2);
        rs += __shfl_xor(rs, 4);
        rs += __shfl_xor(rs, 8);
        l_i[rt][r] = l_i[rt][r] * alpha + rs;
#pragma unroll
        for (int df = 0; df < 8; ++df) oacc[rt][df][r] *= alpha;
      }
    }

    // ---- P: C-layout -> LDS -> A-layout (per-wave buffer, no block sync needed) ----
#pragma unroll
    for (int rt = 0; rt < 2; ++rt)
#pragma unroll
      for (int cf = 0; cf < 4; ++cf)
#pragma unroll
        for (int r = 0; r < 4; ++r)
          pw[(rt * 16 + quad * 4 + r) * PSTR + cf * 16 + ln] = (short)f2bf(sacc[rt][cf][r]);

    short8 pfrag[2][2];
#pragma unroll
    for (int rt = 0; rt < 2; ++rt)
#pragma unroll
      for (int sc = 0; sc < 2; ++sc)
        pfrag[rt][sc] = *(const short8*)&pw[(rt * 16 + ln) * PSTR + sc * 32 + quad * 8];

    // ---- O += P V : V B-frags contiguous from transposed LDS ----
#pragma unroll
    for (int sc = 0; sc < 2; ++sc) {
#pragma unroll
      for (int df = 0; df < 8; ++df) {
        short8 vf = *(const short8*)&vbufT[(df * 16 + ln) * VSTR + sc * 32 + quad * 8];
        oacc[0][df] = __builtin_amdgcn_mfma_f32_16x16x32_bf16(pfrag[0][sc], vf, oacc[0][df], 0, 0, 0);
        oacc[1][df] = __builtin_amdgcn_mfma_f32_16x16x32_bf16(pfrag[1][sc], vf, oacc[1][df], 0, 0, 0);
      }
    }
  }

  // ---- epilogue: normalize by l and store fp32 ----
#pragma unroll
  for (int rt = 0; rt < 2; ++rt) {
#pragma unroll
    for (int r = 0; r < 4; ++r) {
      float inv = 1.f / l_i[rt][r];
      float* op = O + boff + (size_t)(qbase + rt * 16 + quad * 4 + r) * D_DIM;
#pragma unroll
      for (int df = 0; df < 8; ++df)
        op[df * 16 + ln] = oacc[rt][df][r] * inv;
    }
  }
}

extern "C" void kernel_launch(void* const* d_in, const int* in_sizes, int n_in,
                              void* d_out, int out_size, void* d_ws, size_t ws_size,
                              hipStream_t stream) {
  const float* Q = (const float*)d_in[0];
  const float* K = (const float*)d_in[1];
  const float* V = (const float*)d_in[2];
  float* O = (float*)d_out;
  attn_kernel<<<dim3(256), dim3(256), 0, stream>>>(Q, K, V, O);
}

// Round 2
// 162.624 us; speedup vs baseline: 1.5974x; 1.5974x over previous
//
#include <hip/hip_runtime.h>

#define S_LEN 2048
#define D_DIM 128
#define TK 64
#define KSTR 136   // kbuf row stride (bf16 elems): 128 + 8 pad
#define VSTR 72    // vbufT row stride: 64 + 8 pad
#define PSTR 72    // pbuf row stride
#define NT (S_LEN / TK)
#define NWAVE 8

typedef __attribute__((ext_vector_type(4))) float f32x4;
typedef __attribute__((ext_vector_type(8))) short short8;

static __device__ __forceinline__ unsigned short f2bf(float f) {
  unsigned u = __builtin_bit_cast(unsigned, f);
  return (unsigned short)((u + 0x7fffu + ((u >> 16) & 1u)) >> 16);  // RNE
}

__global__ __launch_bounds__(512, 2)
void attn_kernel(const float* __restrict__ Q, const float* __restrict__ K,
                 const float* __restrict__ V, float* __restrict__ O) {
  __shared__ short kbuf[TK * KSTR];          // 64 x 136 bf16 (K tile, row-major)
  __shared__ short vbufT[D_DIM * VSTR];      // 128 x 72 bf16 (V^T tile: [d][s])
  __shared__ short pbuf[NWAVE * 16 * PSTR];  // per-wave 16 x 72 bf16 (P round-trip)

  const int tid  = threadIdx.x;
  const int wave = tid >> 6;
  const int lane = tid & 63;
  const int quad = lane >> 4;
  const int ln   = lane & 15;

  // XCD-aware swizzle: batch pair pinned to one XCD for K/V L2 residency
  const int i     = blockIdx.x;
  const int b     = (i & 7) * 2 + ((i >> 3) & 1);
  const int qtile = i >> 4;                       // 0..15
  const int qbase = qtile * 128 + wave * 16;      // this wave's 16 q-rows

  const size_t boff = (size_t)b * S_LEN * D_DIM;
  const float* Qb = Q + boff;
  const float* Kb = K + boff;
  const float* Vb = V + boff;

  // staging thread coords
  const int rbase = tid >> 5;   // 0..15
  const int c4    = tid & 31;   // 0..31

  // ---- Q fragments (A-layout: row=ln, k=quad*8+j) ----
  short8 qa[4];
  {
    const float* qp = Qb + (size_t)(qbase + ln) * D_DIM + quad * 8;
#pragma unroll
    for (int dc = 0; dc < 4; ++dc) {
      float4 a0 = *(const float4*)(qp + dc * 32);
      float4 a1 = *(const float4*)(qp + dc * 32 + 4);
      short8 f;
      f[0] = (short)f2bf(a0.x); f[1] = (short)f2bf(a0.y);
      f[2] = (short)f2bf(a0.z); f[3] = (short)f2bf(a0.w);
      f[4] = (short)f2bf(a1.x); f[5] = (short)f2bf(a1.y);
      f[6] = (short)f2bf(a1.z); f[7] = (short)f2bf(a1.w);
      qa[dc] = f;
    }
  }

  const f32x4 zf = {0.f, 0.f, 0.f, 0.f};
  f32x4 oacc[8];
  float lsum[4] = {0.f, 0.f, 0.f, 0.f};
#pragma unroll
  for (int df = 0; df < 8; ++df) oacc[df] = zf;

  // ---- prefetch tile 0 ----
  float4 kr[4];
  float  vr[4][4];   // [k][r] : V[(rbase*4+r)][c4 + 32k]
#pragma unroll
  for (int j = 0; j < 4; ++j)
    kr[j] = *(const float4*)(Kb + (rbase + 16 * j) * D_DIM + c4 * 4);
#pragma unroll
  for (int k = 0; k < 4; ++k)
#pragma unroll
    for (int r = 0; r < 4; ++r)
      vr[k][r] = Vb[(rbase * 4 + r) * D_DIM + c4 + 32 * k];

  const float SC = 0.08838834764831845f * 1.4426950408889634f; // 1/sqrt(128)*log2(e)
  short* pw = pbuf + wave * 16 * PSTR;

  for (int t = 0; t < NT; ++t) {
    __syncthreads();  // previous tile's LDS reads complete

    // ---- K tile -> LDS (bf16 row-major, conflict-free) ----
#pragma unroll
    for (int j = 0; j < 4; ++j) {
      unsigned lo = (unsigned)f2bf(kr[j].x) | ((unsigned)f2bf(kr[j].y) << 16);
      unsigned hi = (unsigned)f2bf(kr[j].z) | ((unsigned)f2bf(kr[j].w) << 16);
      *(uint2*)&kbuf[(rbase + 16 * j) * KSTR + c4 * 4] = make_uint2(lo, hi);
    }
    // ---- V tile -> LDS transposed; per-lane d-column -> banks spread fully ----
#pragma unroll
    for (int k = 0; k < 4; ++k) {
      unsigned lo = (unsigned)f2bf(vr[k][0]) | ((unsigned)f2bf(vr[k][1]) << 16);
      unsigned hi = (unsigned)f2bf(vr[k][2]) | ((unsigned)f2bf(vr[k][3]) << 16);
      *(uint2*)&vbufT[(c4 + 32 * k) * VSTR + rbase * 4] = make_uint2(lo, hi);
    }

    // ---- prefetch next tile ----
    if (t + 1 < NT) {
      const float* ksrc = Kb + (size_t)(t + 1) * TK * D_DIM;
      const float* vsrc = Vb + (size_t)(t + 1) * TK * D_DIM;
#pragma unroll
      for (int j = 0; j < 4; ++j)
        kr[j] = *(const float4*)(ksrc + (rbase + 16 * j) * D_DIM + c4 * 4);
#pragma unroll
      for (int k = 0; k < 4; ++k)
#pragma unroll
        for (int r = 0; r < 4; ++r)
          vr[k][r] = vsrc[(rbase * 4 + r) * D_DIM + c4 + 32 * k];
    }
    __syncthreads();  // staging visible

    // ---- S = Q K^T : 16 rows x 64 cols, K=128 over 4 MFMAs ----
    f32x4 sacc[4];
#pragma unroll
    for (int cf = 0; cf < 4; ++cf) sacc[cf] = zf;
#pragma unroll
    for (int cf = 0; cf < 4; ++cf) {
#pragma unroll
      for (int dc = 0; dc < 4; ++dc) {
        short8 kf = *(const short8*)&kbuf[(cf * 16 + ln) * KSTR + dc * 32 + quad * 8];
        sacc[cf] = __builtin_amdgcn_mfma_f32_16x16x32_bf16(qa[dc], kf, sacc[cf], 0, 0, 0);
      }
    }

    // ---- max-free softmax: p = exp2(s*SC); lazy row-sum accumulation ----
#pragma unroll
    for (int cf = 0; cf < 4; ++cf) {
#pragma unroll
      for (int r = 0; r < 4; ++r) {
        float p = exp2f(sacc[cf][r] * SC);
        sacc[cf][r] = p;
        lsum[r] += p;
      }
    }

    // ---- P: C-layout -> LDS -> A-layout (per-wave buffer) ----
#pragma unroll
    for (int cf = 0; cf < 4; ++cf)
#pragma unroll
      for (int r = 0; r < 4; ++r)
        pw[(quad * 4 + r) * PSTR + cf * 16 + ln] = (short)f2bf(sacc[cf][r]);

    short8 pfrag[2];
#pragma unroll
    for (int sc = 0; sc < 2; ++sc)
      pfrag[sc] = *(const short8*)&pw[ln * PSTR + sc * 32 + quad * 8];

    // ---- O += P V ----
#pragma unroll
    for (int sc = 0; sc < 2; ++sc) {
#pragma unroll
      for (int df = 0; df < 8; ++df) {
        short8 vf = *(const short8*)&vbufT[(df * 16 + ln) * VSTR + sc * 32 + quad * 8];
        oacc[df] = __builtin_amdgcn_mfma_f32_16x16x32_bf16(pfrag[sc], vf, oacc[df], 0, 0, 0);
      }
    }
  }

  // ---- final l reduction over the 16-lane col dimension ----
#pragma unroll
  for (int r = 0; r < 4; ++r) {
    float s = lsum[r];
    s += __shfl_xor(s, 1);
    s += __shfl_xor(s, 2);
    s += __shfl_xor(s, 4);
    s += __shfl_xor(s, 8);
    lsum[r] = 1.f / s;
  }

  // ---- epilogue: normalize and store fp32 ----
#pragma unroll
  for (int r = 0; r < 4; ++r) {
    float* op = O + boff + (size_t)(qbase + quad * 4 + r) * D_DIM;
#pragma unroll
    for (int df = 0; df < 8; ++df)
      op[df * 16 + ln] = oacc[df][r] * lsum[r];
  }
}

extern "C" void kernel_launch(void* const* d_in, const int* in_sizes, int n_in,
                              void* d_out, int out_size, void* d_ws, size_t ws_size,
                              hipStream_t stream) {
  const float* Q = (const float*)d_in[0];
  const float* K = (const float*)d_in[1];
  const float* V = (const float*)d_in[2];
  float* O = (float*)d_out;
  attn_kernel<<<dim3(256), dim3(512), 0, stream>>>(Q, K, V, O);
}